// Round 7
// baseline (589.465 us; speedup 1.0000x reference)
//
#include <hip/hip_runtime.h>
#include <hip/hip_bf16.h>
#include <stdint.h>

#define NB 4096
#define ND 256
#define NC 32000
#define WR 64                 // block tile rows
#define WC 640                // block tile cols (per-row write span = 2560B)
#define NRT (NB / WR)         // 64 row-tiles
#define NCT (NC / WC)         // 50 col-tiles

typedef __bf16 bf16x8 __attribute__((ext_vector_type(8)));
typedef float  f32x4  __attribute__((ext_vector_type(4)));

__device__ __forceinline__ unsigned short f32_to_bf16(float f) {
  union { float f; uint32_t u; } v; v.f = f;
  uint32_t r = v.u + 0x7fffu + ((v.u >> 16) & 1u);
  return (unsigned short)(r >> 16);
}

// Cast inputs/V to bf16 in workspace; zero loss accumulator.
__global__ void prep_kernel(const float* __restrict__ inA,
                            const float* __restrict__ inV,
                            unsigned short* __restrict__ outA,
                            unsigned short* __restrict__ outV,
                            float* __restrict__ loss) {
  int gid = blockIdx.x * blockDim.x + threadIdx.x;
  int stride = gridDim.x * blockDim.x;
  if (gid == 0) *loss = 0.f;
  const int nA4 = NB * ND / 4;   // 262144
  const int nV4 = NC * ND / 4;   // 2048000
  for (int i = gid; i < nA4 + nV4; i += stride) {
    float4 v = (i < nA4) ? ((const float4*)inA)[i]
                         : ((const float4*)inV)[i - nA4];
    ushort4 o;
    o.x = f32_to_bf16(v.x);
    o.y = f32_to_bf16(v.y);
    o.z = f32_to_bf16(v.z);
    o.w = f32_to_bf16(v.w);
    if (i < nA4) ((ushort4*)outA)[i] = o;
    else         ((ushort4*)outV)[i - nA4] = o;
  }
}

// Wide-tile GEMM for write locality: 64x640 block, 8 waves = 4 row-frags x
// 2 col-groups; wave = 16 rows x 320 cols = acc[20] 16x16 frags (swapped
// operands -> lane regs = 4 consecutive out cols). Fragments loaded directly
// from global (V col-slice ~2.2MB L2-resident per XCD; A LLC-resident).
// No LDS/barriers in K-loop. Per-wave contiguous write span = 1280B/row
// (vs 256B in R1-R6 -- testing the DRAM write-locality theory of the
// constant ~2.2 TB/s wall). Cached (non-NT) stores: L2 merges the +4B-phase
// misalignment (R6 showed NT amplifies writes 1.53x).
__global__ void __launch_bounds__(512, 2)
gemm_expsum_kernel(const unsigned short* __restrict__ A,
                   const unsigned short* __restrict__ V,
                   float* __restrict__ out,       // d_out + 1
                   float* __restrict__ partial) { // [NCT][NB]
  __shared__ float red[2][64];

  // per-XCD contiguous work stream: XCD owns ~6.25 col-tiles, rowt-fast
  const int b = blockIdx.x;
  const int g = (b & 7) * (NRT * NCT / 8) + (b >> 3);   // bijective, 3200
  const int colt = g >> 6;          // g / 64  (0..49)
  const int rowt = g & 63;          // g % 64
  const int brow = rowt * WR;
  const int bcol = colt * WC;

  const int tid  = threadIdx.x;
  const int lane = tid & 63;
  const int wave = tid >> 6;
  const int rf   = wave & 3;       // row-frag 0..3 (16 rows each)
  const int cg   = wave >> 2;      // col-group 0..1 (320 cols each)
  const int c16  = lane & 15;
  const int kq   = lane >> 4;      // 0..3

  const __bf16* Ab = (const __bf16*)A;
  const __bf16* Vb = (const __bf16*)V;
  const __bf16* aB = Ab + (size_t)(brow + rf * 16 + c16) * ND + kq * 8;
  const __bf16* vB = Vb + (size_t)(bcol + cg * 320 + c16) * ND + kq * 8;

  f32x4 acc[20];
#pragma unroll
  for (int f = 0; f < 20; ++f) acc[f] = (f32x4){0.f, 0.f, 0.f, 0.f};

#pragma unroll
  for (int kt = 0; kt < 8; ++kt) {
    bf16x8 af = *(const bf16x8*)(aB + kt * 32);
    bf16x8 vf[20];
#pragma unroll
    for (int f = 0; f < 20; ++f)
      vf[f] = *(const bf16x8*)(vB + (size_t)f * 16 * ND + kt * 32);
#pragma unroll
    for (int f = 0; f < 20; ++f)
      acc[f] = __builtin_amdgcn_mfma_f32_16x16x32_bf16(vf[f], af, acc[f],
                                                       0, 0, 0);
  }

  // Epilogue: contiguous float4 stores + fused exp-rowsum (no atomics).
  // acc[f] reg q -> out[brow+rf*16+c16][bcol+cg*320+f*16+kq*4+q]
  const int grow = brow + rf * 16 + c16;
  float* prow = out + (size_t)grow * NC + (bcol + cg * 320 + kq * 4);
  float rsum = 0.f;
#pragma unroll
  for (int f = 0; f < 20; ++f) {
    f32x4 v = acc[f];
    *(f32x4*)(prow + f * 16) = v;
    rsum += __expf(v[0]) + __expf(v[1]) + __expf(v[2]) + __expf(v[3]);
  }
  rsum += __shfl_xor(rsum, 16);
  rsum += __shfl_xor(rsum, 32);
  if (lane < 16) red[cg][rf * 16 + c16] = rsum;
  __syncthreads();
  if (tid < 64)
    partial[(size_t)colt * NB + brow + tid] = red[0][tid] + red[1][tid];
}

// loss = mean_r( log(sum_c partial[c][r]) - out[r, targets[r]] )
__global__ void finalize_kernel(const float* __restrict__ partial,
                                const float* __restrict__ out,  // d_out + 1
                                const int* __restrict__ targets,
                                float* __restrict__ loss) {
  int r = blockIdx.x * blockDim.x + threadIdx.x;   // 0..NB-1
  float s = 0.f;
#pragma unroll 5
  for (int c = 0; c < NCT; ++c) s += partial[(size_t)c * NB + r];
  float li = logf(s) - out[(size_t)r * NC + targets[r]];
#pragma unroll
  for (int o = 32; o > 0; o >>= 1) li += __shfl_down(li, o);
  __shared__ float wsum[4];
  int lane = threadIdx.x & 63, wv = threadIdx.x >> 6;
  if (lane == 0) wsum[wv] = li;
  __syncthreads();
  if (threadIdx.x == 0) {
    float bs = wsum[0] + wsum[1] + wsum[2] + wsum[3];
    atomicAdd(loss, bs * (1.0f / NB));
  }
}

extern "C" void kernel_launch(void* const* d_in, const int* in_sizes, int n_in,
                              void* d_out, int out_size, void* d_ws, size_t ws_size,
                              hipStream_t stream) {
  const float* inputs  = (const float*)d_in[0];
  const int*   targets = (const int*)d_in[1];
  // d_in[2] indexs, d_in[3] label_to_pairs, d_in[4] all_label_to_clusterid: unused (W_MS = 0)
  const float* V       = (const float*)d_in[5];

  float* loss    = (float*)d_out;          // output 0: scalar loss
  float* outputs = (float*)d_out + 1;      // output 1: [4096][32000]

  char* ws = (char*)d_ws;
  unsigned short* Abf = (unsigned short*)ws;                              // 2 MB
  unsigned short* Vbf = (unsigned short*)(ws + (size_t)NB * ND * 2);      // 16.4 MB
  float* partial = (float*)(ws + (size_t)NB * ND * 2 + (size_t)NC * ND * 2); // 800 KB

  hipLaunchKernelGGL(prep_kernel, dim3(2048), dim3(256), 0, stream,
                     inputs, V, Abf, Vbf, loss);
  hipLaunchKernelGGL(gemm_expsum_kernel, dim3(NRT * NCT), dim3(512), 0, stream,
                     Abf, Vbf, outputs, partial);
  hipLaunchKernelGGL(finalize_kernel, dim3(NB / 256), dim3(256), 0, stream,
                     partial, outputs, targets, loss);
}

// Round 8
// 352.630 us; speedup vs baseline: 1.6716x; 1.6716x over previous
//
#include <hip/hip_runtime.h>
#include <hip/hip_bf16.h>
#include <stdint.h>

#define NB 4096
#define ND 256
#define NC 32000
#define NCT (NC / 128)   // 250 col-tiles

typedef __bf16 bf16x8 __attribute__((ext_vector_type(8)));
typedef float  f32x4  __attribute__((ext_vector_type(4)));

__device__ __forceinline__ unsigned short f32_to_bf16(float f) {
  union { float f; uint32_t u; } v; v.f = f;
  uint32_t r = v.u + 0x7fffu + ((v.u >> 16) & 1u);
  return (unsigned short)(r >> 16);
}

// Cast inputs/V to bf16 in workspace; zero loss accumulator.
__global__ void prep_kernel(const float* __restrict__ inA,
                            const float* __restrict__ inV,
                            unsigned short* __restrict__ outA,
                            unsigned short* __restrict__ outV,
                            float* __restrict__ loss) {
  int gid = blockIdx.x * blockDim.x + threadIdx.x;
  int stride = gridDim.x * blockDim.x;
  if (gid == 0) *loss = 0.f;
  const int nA4 = NB * ND / 4;   // 262144
  const int nV4 = NC * ND / 4;   // 2048000
  for (int i = gid; i < nA4 + nV4; i += stride) {
    float4 v = (i < nA4) ? ((const float4*)inA)[i]
                         : ((const float4*)inV)[i - nA4];
    ushort4 o;
    o.x = f32_to_bf16(v.x);
    o.y = f32_to_bf16(v.y);
    o.z = f32_to_bf16(v.z);
    o.w = f32_to_bf16(v.w);
    if (i < nA4) ((ushort4*)outA)[i] = o;
    else         ((ushort4*)outV)[i - nA4] = o;
  }
}

// R5 base (best so far, 310us): barrier-free K-loop, direct global frag
// loads, swapped-operand MFMA, XCD-swizzled grid, partial-array expsum.
// NEW (the single variable): ALIGNED output stores. d_out+1 puts every
// row at +4B phase; R1-R7 stored f32x4 at addr===4 (mod 16) -> every store
// split in two by the memory pipe (structure-invariant ~2.2 TB/s wall).
// Here each lane stores the aligned chunk [col 3+4t, 7+4t) assembled
// in-register via one __shfl from lane+16; the ragged edge cols {0,1,2,63}
// are stored as naturally-aligned b32 by the t==15 lanes.
__global__ void __launch_bounds__(256, 2)
gemm_expsum_kernel(const unsigned short* __restrict__ A,
                   const unsigned short* __restrict__ V,
                   float* __restrict__ out,       // d_out + 1 (4B phase!)
                   float* __restrict__ partial) { // [NCT][NB]
  __shared__ float red[2][128];

  const int b = blockIdx.x;
  const int xcd = b & 7;
  const int s = b >> 3;                     // 0..1023 per XCD
  const int colt = (xcd << 5) + (s & 31);   // 32 col-tiles per XCD, col-fast
  const int rowt = s >> 5;                  // 0..31
  if (colt >= NCT) return;                  // padded tail (colt 250..255)
  const int brow = rowt << 7;
  const int bcol = colt << 7;

  const int tid  = threadIdx.x;
  const int lane = tid & 63;
  const int wave = tid >> 6;
  const int wr   = wave >> 1;
  const int wc   = wave & 1;
  const int c16  = lane & 15;
  const int kq   = lane >> 4;      // 0..3

  const __bf16* Ab = (const __bf16*)A;
  const __bf16* Vb = (const __bf16*)V;
  const __bf16* aBase = Ab + (size_t)(brow + wr * 64 + c16) * ND + kq * 8;
  const __bf16* bBase = Vb + (size_t)(bcol + wc * 64 + c16) * ND + kq * 8;

  f32x4 acc[4][4];   // acc[c][r]: c = V-frag (out cols), r = A-frag (out rows)
#pragma unroll
  for (int c = 0; c < 4; ++c)
#pragma unroll
    for (int r = 0; r < 4; ++r)
      acc[c][r] = (f32x4){0.f, 0.f, 0.f, 0.f};

  bf16x8 a0[4], b0[4], a1[4], b1[4];

#define LOADF(AF, BF, KT)                                                     \
  do {                                                                        \
    _Pragma("unroll")                                                         \
    for (int m = 0; m < 4; ++m)                                               \
      AF[m] = *(const bf16x8*)(aBase + (size_t)m * 16 * ND + (KT) * 32);      \
    _Pragma("unroll")                                                         \
    for (int n = 0; n < 4; ++n)                                               \
      BF[n] = *(const bf16x8*)(bBase + (size_t)n * 16 * ND + (KT) * 32);      \
  } while (0)

#define MFMAALL(AF, BF)                                                       \
  do {                                                                        \
    _Pragma("unroll")                                                         \
    for (int c = 0; c < 4; ++c)                                               \
      _Pragma("unroll")                                                       \
      for (int r = 0; r < 4; ++r)                                             \
        acc[c][r] = __builtin_amdgcn_mfma_f32_16x16x32_bf16(BF[c], AF[r],     \
                                                            acc[c][r], 0, 0, 0); \
  } while (0)

  LOADF(a0, b0, 0);
#pragma unroll
  for (int kt = 0; kt < 8; kt += 2) {
    if (kt + 1 < 8) LOADF(a1, b1, kt + 1);
    MFMAALL(a0, b0);
    if (kt + 2 < 8) LOADF(a0, b0, kt + 2);
    MFMAALL(a1, b1);
  }

  // Epilogue: ALIGNED stores via -1-column rotate across lanes.
  // Value-chunk v# = 4c+kq holds cols [16c+4kq .. +4). Aligned out-chunk
  // t = 4c+kq covers cols [3+4t, 7+4t):
  //   F[0]   = own acc[c][r][3]            (col 3+4t)
  //   F[1+j] = acc[.][r][j] of lane+16     (cols 4+4t..6+4t)
  // where lane+16 wraps kq 3->0 carrying c -> c+1 (and c=3 -> chunk {63,0,1,2}).
  const int colbase = bcol + wc * 64;
  const int srcl = (lane + 16) & 63;
#pragma unroll
  for (int r = 0; r < 4; ++r) {
    const int grow = brow + wr * 64 + r * 16 + c16;
    float* prow0 = out + (size_t)grow * NC + colbase;
    float rsum = 0.f;
#pragma unroll
    for (int c = 0; c < 4; ++c) {
      f32x4 a = acc[c][r];
      rsum += __expf(a[0]) + __expf(a[1]) + __expf(a[2]) + __expf(a[3]);
      // source value for the receiver one kq below (kq==0 sources acc[c+1])
      const int cs = (c + 1) & 3;
      float g0 = (kq == 0) ? acc[cs][r][0] : a[0];
      float g1 = (kq == 0) ? acc[cs][r][1] : a[1];
      float g2 = (kq == 0) ? acc[cs][r][2] : a[2];
      f32x4 F;
      F[0] = a[3];
      F[1] = __shfl(g0, srcl);
      F[2] = __shfl(g1, srcl);
      F[3] = __shfl(g2, srcl);
      const int t = c * 4 + kq;
      if (t < 15) {
        *(f32x4*)(prow0 + 3 + 4 * t) = F;     // dword idx === 0 (mod 4)
      } else {                                 // chunk {63, 0, 1, 2}
        prow0[63] = F[0];
        prow0[0]  = F[1];
        prow0[1]  = F[2];
        prow0[2]  = F[3];
      }
    }
    rsum += __shfl_xor(rsum, 16);
    rsum += __shfl_xor(rsum, 32);
    if (lane < 16) red[wc][wr * 64 + r * 16 + c16] = rsum;
  }
  __syncthreads();
  if (tid < 128)
    partial[(size_t)colt * NB + brow + tid] = red[0][tid] + red[1][tid];
#undef LOADF
#undef MFMAALL
}

// loss = mean_r( log(sum_c partial[c][r]) - out[r, targets[r]] )
__global__ void finalize_kernel(const float* __restrict__ partial,
                                const float* __restrict__ out,  // d_out + 1
                                const int* __restrict__ targets,
                                float* __restrict__ loss) {
  int r = blockIdx.x * blockDim.x + threadIdx.x;   // 0..NB-1
  float s = 0.f;
  for (int c = 0; c < NCT; ++c) s += partial[(size_t)c * NB + r];
  float li = logf(s) - out[(size_t)r * NC + targets[r]];
#pragma unroll
  for (int o = 32; o > 0; o >>= 1) li += __shfl_down(li, o);
  __shared__ float wsum[4];
  int lane = threadIdx.x & 63, wv = threadIdx.x >> 6;
  if (lane == 0) wsum[wv] = li;
  __syncthreads();
  if (threadIdx.x == 0) {
    float bs = wsum[0] + wsum[1] + wsum[2] + wsum[3];
    atomicAdd(loss, bs * (1.0f / NB));
  }
}

extern "C" void kernel_launch(void* const* d_in, const int* in_sizes, int n_in,
                              void* d_out, int out_size, void* d_ws, size_t ws_size,
                              hipStream_t stream) {
  const float* inputs  = (const float*)d_in[0];
  const int*   targets = (const int*)d_in[1];
  // d_in[2] indexs, d_in[3] label_to_pairs, d_in[4] all_label_to_clusterid: unused (W_MS = 0)
  const float* V       = (const float*)d_in[5];

  float* loss    = (float*)d_out;          // output 0: scalar loss
  float* outputs = (float*)d_out + 1;      // output 1: [4096][32000]

  char* ws = (char*)d_ws;
  unsigned short* Abf = (unsigned short*)ws;                              // 2 MB
  unsigned short* Vbf = (unsigned short*)(ws + (size_t)NB * ND * 2);      // 16.4 MB
  float* partial = (float*)(ws + (size_t)NB * ND * 2 + (size_t)NC * ND * 2); // 3.9 MB

  hipLaunchKernelGGL(prep_kernel, dim3(2048), dim3(256), 0, stream,
                     inputs, V, Abf, Vbf, loss);
  // grid: 8 XCDs x 1024 (32 col-tiles x 32 row-tiles), col-tiles padded to 256
  hipLaunchKernelGGL(gemm_expsum_kernel, dim3(8 * 1024), dim3(256), 0, stream,
                     Abf, Vbf, outputs, partial);
  hipLaunchKernelGGL(finalize_kernel, dim3(NB / 256), dim3(256), 0, stream,
                     partial, outputs, targets, loss);
}